// Round 11
// baseline (464.923 us; speedup 1.0000x reference)
//
#include <hip/hip_runtime.h>
#include <hip/hip_bf16.h>

#define DEVINL __device__ __forceinline__

typedef __attribute__((ext_vector_type(8)))  short short8;
typedef __attribute__((ext_vector_type(4)))  float float4v;

DEVINL float bf2f(unsigned short u) { return __uint_as_float(((unsigned)u) << 16); }
DEVINL unsigned short f2bf(float f) {            // round-to-nearest-even
  unsigned u = __float_as_uint(f);
  unsigned r = u + 0x7FFFu + ((u >> 16) & 1u);
  return (unsigned short)(r >> 16);
}

// region: 0=center,1=TL,2=top,3=TR,4=right,5=BR,6=bottom,7=BL,8=left
DEVINL int region_of(int h, int w, int n) {
  if (h == 0)     return (w == 0) ? 1 : ((w == n-1) ? 3 : 2);
  if (h == n-1)   return (w == 0) ? 7 : ((w == n-1) ? 5 : 6);
  return (w == 0) ? 8 : ((w == n-1) ? 4 : 0);
}

__global__ void sentinel_k(float* out, float v) {
  int t = blockIdx.x*64 + threadIdx.x;
  if (t < 320) out[t] = v;
}

union ABu { float4 f4; short8 v; };

// hand-rolled grid barrier: one single-use counter per phase.
// release fence (L2 wb) -> device-scope atomicAdd -> agent-scope spin ->
// acquire fence (L2 inv). All 512 blocks co-resident (2/CU at 4/CU capacity).
DEVINL void gridbar(unsigned* cnt, unsigned nb) {
  __syncthreads();
  if (threadIdx.x == 0) {
    __threadfence();
    atomicAdd(cnt, 1u);
    while (__hip_atomic_load(cnt, __ATOMIC_RELAXED, __HIP_MEMORY_SCOPE_AGENT) < nb)
      __builtin_amdgcn_s_sleep(2);
    __threadfence();
  }
  __syncthreads();
}

// ---- the whole network in one kernel, plain launch + manual grid barrier ----
// Grid 512 x 256. LDS max 38016 B (capacity 4/CU); __launch_bounds__(256,2)
// needs only 2/CU -> 2x co-residency margin.
__global__ __launch_bounds__(256, 2) void mega_k(
    const float* __restrict__ x,
    const float* __restrict__ Wc1, const float* __restrict__ Dc1,
    const float* __restrict__ Wc2, const float* __restrict__ Dc2,
    const float* __restrict__ Wc3, const float* __restrict__ Dc3,
    const float* __restrict__ Wc4, const float* __restrict__ Dc4,
    const float* __restrict__ Wd1, const float* __restrict__ Dd1,
    const float* __restrict__ Wo,  const float* __restrict__ Do,
    char* __restrict__ wsb, float* __restrict__ out)
{
  __shared__ __align__(16) char smem[38016];

  int bb = blockIdx.x, t = threadIdx.x;
  int lane = t & 63, wave = t >> 6, quad = (t >> 4) & 3, lm = t & 15;

  unsigned* bar = (unsigned*)wsb;                              // 6 slots, memset 0
  unsigned short* Wt2 = (unsigned short*)(wsb + (1u << 20));
  unsigned short* Wt3 = (unsigned short*)(wsb + (1u << 20) + 262144);
  unsigned short* Wt4 = (unsigned short*)(wsb + (1u << 20) + 524288);
  unsigned short* U1  = (unsigned short*)(wsb + (2u  << 20)); // 16.8 MB
  unsigned short* P2  = (unsigned short*)(wsb + (19u << 20)); // 4.2 MB
  unsigned short* U3  = (unsigned short*)(wsb + (2u  << 20)); // 8.4 MB (U1 dead)
  unsigned short* P4  = (unsigned short*)(wsb + (19u << 20)); // 2.1 MB (P2 dead)
  float*          part = (float*)(wsb + (2u  << 20));         // 8.4 MB (U3 dead)

  // ---------- P0a: weight transposes into MFMA B-frag layout ----------
  {
    int i = bb*256 + t;   // 512*256 = 131072 slots >= 32256 work items
    if (i < 32256) {
      const float* W; unsigned short* T; int NT, F, li;
      if (i < 4608)       { W = Wc2; T = Wt2; NT = 4; F = 64;  li = i; }
      else if (i < 13824) { W = Wc3; T = Wt3; NT = 8; F = 128; li = i - 4608; }
      else                { W = Wc4; T = Wt4; NT = 8; F = 128; li = i - 13824; }
      int l = li & 63, nt = (li >> 6) % NT, kstep = li / (64*NT);
      int f = nt*16 + (l & 15);
      int kbase = kstep*32 + (l >> 4)*8;
      unsigned short v[8];
      #pragma unroll
      for (int j = 0; j < 8; j++) v[j] = f2bf(W[(kbase + j)*F + f]);
      ushort4* q = (ushort4*)&T[(size_t)li * 8];
      q[0] = make_ushort4(v[0], v[1], v[2], v[3]);
      q[1] = make_ushort4(v[4], v[5], v[6], v[7]);
    }
  }
  // ---------- P0b: conv1 (C=1 -> 64, vector ALU), 4 units/block ----------
  {
    float (*a)[66] = (float(*)[66])smem;
    for (int u = bb; u < 2048; u += 512) {
      int b = u >> 6, h = u & 63;
      __syncthreads();
      for (int idx = t; idx < 3*66; idx += 256) {
        int dy = idx / 66, wcol = idx % 66;
        int hh = h + dy - 1, w = wcol - 1;
        float v = 0.f;
        if (hh >= 0 && hh < 64 && w >= 0 && w < 64) v = x[(b*64 + hh)*64 + w];
        a[dy][wcol] = v;
      }
      __syncthreads();
      int f = t & 63, wq = t >> 6;
      float wk[9];
      #pragma unroll
      for (int k = 0; k < 9; k++) wk[k] = Wc1[k*64 + f];
      for (int wi = 0; wi < 16; wi++) {
        int w = wq*16 + wi;
        float acc = 0.f;
        #pragma unroll
        for (int dy = 0; dy < 3; dy++)
          #pragma unroll
          for (int dx = 0; dx < 3; dx++)
            acc += a[dy][w+dx] * wk[dy*3+dx];
        int r = region_of(h, w, 64);
        U1[(((size_t)b*64 + h)*64 + w)*64 + f] = f2bf(fminf(acc - Dc1[r*64 + f], 0.f));
      }
    }
  }
  gridbar(&bar[0], 512);

  // ---------- P1: conv2 + pool (C=64,F=64,N=64), 1024 units, 2/block ----------
  {
    unsigned short* lds = (unsigned short*)smem;  // 4*66*72*2 = 38016
    for (int u = bb; u < 1024; u += 512) {
      int b = u >> 5, hp = u & 31, h0 = hp*2;
      __syncthreads();
      for (int i = t; i < 4*66*8; i += 256) {
        int c8 = i & 7, wc = (i >> 3) % 66, r = i / (8*66);
        int hh = h0 - 1 + r, w = wc - 1;
        float4 v = make_float4(0.f,0.f,0.f,0.f);
        if (hh >= 0 && hh < 64 && w >= 0 && w < 64)
          v = *(const float4*)&U1[(((size_t)b*64 + hh)*64 + w)*64 + c8*8];
        *(float4*)&lds[(r*66 + wc)*72 + c8*8] = v;
      }
      __syncthreads();
      float4v acc[2][4];
      #pragma unroll
      for (int hi = 0; hi < 2; hi++)
        #pragma unroll
        for (int n = 0; n < 4; n++) acc[hi][n] = (float4v){0.f,0.f,0.f,0.f};
      #pragma unroll
      for (int dy = 0; dy < 3; dy++)
      #pragma unroll
      for (int dx = 0; dx < 3; dx++)
      #pragma unroll
      for (int c0 = 0; c0 < 64; c0 += 32) {
        int kstep = (dy*3 + dx)*2 + (c0 >> 5);
        ABu bfr[4];
        #pragma unroll
        for (int n = 0; n < 4; n++)
          bfr[n].f4 = *(const float4*)&Wt2[(size_t)((kstep*4 + n)*64 + lane)*8];
        ABu afr[2];
        #pragma unroll
        for (int hi = 0; hi < 2; hi++)
          afr[hi].f4 = *(const float4*)&lds[((hi+dy)*66 + (wave*16 + lm + dx))*72 + c0 + quad*8];
        #pragma unroll
        for (int hi = 0; hi < 2; hi++)
          #pragma unroll
          for (int n = 0; n < 4; n++)
            acc[hi][n] = __builtin_amdgcn_mfma_f32_16x16x32_bf16(afr[hi].v, bfr[n].v, acc[hi][n], 0, 0, 0);
      }
      #pragma unroll
      for (int n = 0; n < 4; n++) {
        int f = n*16 + lm;
        #pragma unroll
        for (int rp = 0; rp < 2; rp++) {
          float mx = -1e30f;
          #pragma unroll
          for (int hi = 0; hi < 2; hi++)
            #pragma unroll
            for (int rr = 0; rr < 2; rr++) {
              int h = h0 + hi, w = wave*16 + quad*4 + 2*rp + rr;
              mx = fmaxf(mx, fminf(acc[hi][n][2*rp+rr] - Dc2[region_of(h, w, 64)*64 + f], 0.f));
            }
          int wp = wave*8 + quad*2 + rp;
          P2[(((size_t)b*32 + hp)*32 + wp)*64 + f] = f2bf(mx);
        }
      }
    }
  }
  gridbar(&bar[1], 512);

  // ---------- P2: conv3 (C=64,F=128,N=32), 1024 units, 2/block ----------
  {
    unsigned short* lds = (unsigned short*)smem;  // 3*34*72*2 = 14688
    for (int u = bb; u < 1024; u += 512) {
      int b = u >> 5, h = u & 31;
      __syncthreads();
      for (int i = t; i < 3*34*8; i += 256) {
        int c8 = i & 7, wc = (i >> 3) % 34, r = i / (8*34);
        int hh = h - 1 + r, w = wc - 1;
        float4 v = make_float4(0.f,0.f,0.f,0.f);
        if (hh >= 0 && hh < 32 && w >= 0 && w < 32)
          v = *(const float4*)&P2[(((size_t)b*32 + hh)*32 + w)*64 + c8*8];
        *(float4*)&lds[(r*34 + wc)*72 + c8*8] = v;
      }
      __syncthreads();
      int mg = wave >> 1, ng = wave & 1;
      float4v acc[4];
      #pragma unroll
      for (int n = 0; n < 4; n++) acc[n] = (float4v){0.f,0.f,0.f,0.f};
      #pragma unroll
      for (int dy = 0; dy < 3; dy++)
      #pragma unroll
      for (int dx = 0; dx < 3; dx++)
      #pragma unroll
      for (int c0 = 0; c0 < 64; c0 += 32) {
        int kstep = (dy*3 + dx)*2 + (c0 >> 5);
        ABu bfr[4];
        #pragma unroll
        for (int n = 0; n < 4; n++)
          bfr[n].f4 = *(const float4*)&Wt3[(size_t)((kstep*8 + ng*4 + n)*64 + lane)*8];
        ABu afr;
        afr.f4 = *(const float4*)&lds[(dy*34 + (mg*16 + lm + dx))*72 + c0 + quad*8];
        #pragma unroll
        for (int n = 0; n < 4; n++)
          acc[n] = __builtin_amdgcn_mfma_f32_16x16x32_bf16(afr.v, bfr[n].v, acc[n], 0, 0, 0);
      }
      #pragma unroll
      for (int n = 0; n < 4; n++) {
        int f = (ng*4 + n)*16 + lm;
        #pragma unroll
        for (int r = 0; r < 4; r++) {
          int w = mg*16 + quad*4 + r;
          float v = fminf(acc[n][r] - Dc3[region_of(h, w, 32)*128 + f], 0.f);
          U3[(((size_t)b*32 + h)*32 + w)*128 + f] = f2bf(v);
        }
      }
    }
  }
  gridbar(&bar[2], 512);

  // ---------- P3: conv4 + pool (C=128,F=128,N=32), m-split 1024 units, 2/block ----------
  {
    unsigned short* lds = (unsigned short*)smem;  // 4*18*136*2 = 19584
    for (int u = bb; u < 1024; u += 512) {
      int mhalf = u & 1, hp = (u >> 1) & 15, b = u >> 5;
      int h0 = hp*2, w0 = mhalf*16;
      __syncthreads();
      for (int i = t; i < 4*18*16; i += 256) {
        int c8 = i & 15, wc = (i >> 4) % 18, r = i / (16*18);
        int hh = h0 - 1 + r, w = w0 - 1 + wc;
        float4 v = make_float4(0.f,0.f,0.f,0.f);
        if (hh >= 0 && hh < 32 && w >= 0 && w < 32)
          v = *(const float4*)&U3[(((size_t)b*32 + hh)*32 + w)*128 + c8*8];
        *(float4*)&lds[(r*18 + wc)*136 + c8*8] = v;
      }
      __syncthreads();
      int ng = wave;   // 4 waves x 2 n-tiles
      float4v acc[2][2];
      #pragma unroll
      for (int hi = 0; hi < 2; hi++)
        #pragma unroll
        for (int n = 0; n < 2; n++) acc[hi][n] = (float4v){0.f,0.f,0.f,0.f};
      #pragma unroll
      for (int dy = 0; dy < 3; dy++)
      #pragma unroll
      for (int dx = 0; dx < 3; dx++)
      #pragma unroll
      for (int c0 = 0; c0 < 128; c0 += 32) {
        int kstep = (dy*3 + dx)*4 + (c0 >> 5);
        ABu bfr[2];
        #pragma unroll
        for (int n = 0; n < 2; n++)
          bfr[n].f4 = *(const float4*)&Wt4[(size_t)((kstep*8 + ng*2 + n)*64 + lane)*8];
        ABu afr[2];
        #pragma unroll
        for (int hi = 0; hi < 2; hi++)
          afr[hi].f4 = *(const float4*)&lds[((hi+dy)*18 + (lm + dx))*136 + c0 + quad*8];
        #pragma unroll
        for (int hi = 0; hi < 2; hi++)
          #pragma unroll
          for (int n = 0; n < 2; n++)
            acc[hi][n] = __builtin_amdgcn_mfma_f32_16x16x32_bf16(afr[hi].v, bfr[n].v, acc[hi][n], 0, 0, 0);
      }
      #pragma unroll
      for (int n = 0; n < 2; n++) {
        int f = (ng*2 + n)*16 + lm;
        #pragma unroll
        for (int rp = 0; rp < 2; rp++) {
          float mx = -1e30f;
          #pragma unroll
          for (int hi = 0; hi < 2; hi++)
            #pragma unroll
            for (int rr = 0; rr < 2; rr++) {
              int h = h0 + hi, w = w0 + quad*4 + 2*rp + rr;
              mx = fmaxf(mx, fminf(acc[hi][n][2*rp+rr] - Dc4[region_of(h, w, 32)*128 + f], 0.f));
            }
          int wp = mhalf*8 + quad*2 + rp;
          P4[(((size_t)b*16 + hp)*16 + wp)*128 + f] = f2bf(mx);
        }
      }
    }
  }
  gridbar(&bar[3], 512);

  // ---------- P4: dense split-K (512 units, 1/block) ----------
  {
    float (*a)[36] = (float(*)[36])smem;   // 128*36*4 = 18432
    int kblk = bb >> 1, fh = bb & 1, k0 = kblk*128;
    __syncthreads();
    for (int idx = t; idx < 32*128; idx += 256) {
      int bbb = idx >> 7, kc = idx & 127;
      a[kc][bbb] = bf2f(P4[(size_t)bbb*32768 + k0 + kc]);
    }
    __syncthreads();
    int f0 = fh*128 + (t & 31)*4, b0 = (t >> 5)*4;
    float acc[4][4] = {};
    for (int kc = 0; kc < 128; kc++) {
      float4 wv = *(const float4*)&Wd1[(size_t)(k0 + kc)*256 + f0];
      #pragma unroll
      for (int bq = 0; bq < 4; bq++) {
        float av = a[kc][b0 + bq];
        acc[bq][0] += av * wv.x;
        acc[bq][1] += av * wv.y;
        acc[bq][2] += av * wv.z;
        acc[bq][3] += av * wv.w;
      }
    }
    #pragma unroll
    for (int bq = 0; bq < 4; bq++) {
      float4 v = make_float4(acc[bq][0], acc[bq][1], acc[bq][2], acc[bq][3]);
      *(float4*)&part[(size_t)kblk*8192 + (b0+bq)*256 + f0] = v;
    }
  }
  gridbar(&bar[4], 512);

  // ---------- P5: tail (32 units) ----------
  if (bb < 32) {
    float* ud = (float*)smem;
    float s = 0.f;
    #pragma unroll 4
    for (int blk = 0; blk < 256; blk++) s += part[(size_t)blk*8192 + bb*256 + t];
    ud[t] = fminf(s - Dd1[t], 0.f);
    __syncthreads();
    if (t < 10) {
      float acc = 0.f;
      for (int f = 0; f < 256; f++) acc += ud[f] * Wo[f*10 + t];
      out[bb*10 + t] = Do[t] - acc;
    }
  }
}

extern "C" void kernel_launch(void* const* d_in, const int* in_sizes, int n_in,
                              void* d_out, int out_size, void* d_ws, size_t ws_size,
                              hipStream_t stream)
{
  float* outp = (float*)d_out;

  // --- environment asserts with sentinel outputs (validated in R4/R5) ---
  if (n_in != 13) { sentinel_k<<<5, 64, 0, stream>>>(outp, 200.f); return; }
  const int exp_sz[13] = {131072, 576, 576, 36864, 576, 73728, 1152,
                          147456, 1152, 8388608, 256, 2560, 10};
  for (int i = 0; i < 13; i++)
    if (in_sizes[i] != exp_sz[i]) {
      sentinel_k<<<5, 64, 0, stream>>>(outp, 1000.f + 100.f*i); return;
    }
  if (ws_size < (37u << 20)) { sentinel_k<<<5, 64, 0, stream>>>(outp, 500.f); return; }

  char* wsb = (char*)d_ws;
  const float* x    = (const float*)d_in[0];
  const float* Wc1  = (const float*)d_in[1];
  const float* Dc1  = (const float*)d_in[2];
  const float* Wc2  = (const float*)d_in[3];
  const float* Dc2  = (const float*)d_in[4];
  const float* Wc3  = (const float*)d_in[5];
  const float* Dc3  = (const float*)d_in[6];
  const float* Wc4  = (const float*)d_in[7];
  const float* Dc4  = (const float*)d_in[8];
  const float* Wd1  = (const float*)d_in[9];
  const float* Dd1  = (const float*)d_in[10];
  const float* Wout = (const float*)d_in[11];
  const float* Dout = (const float*)d_in[12];

  // zero the 6 grid-barrier counters (ws is re-poisoned 0xAA before each call)
  hipMemsetAsync(wsb, 0, 64, stream);

  mega_k<<<512, 256, 0, stream>>>(x, Wc1, Dc1, Wc2, Dc2, Wc3, Dc3, Wc4, Dc4,
                                  Wd1, Dd1, Wout, Dout, wsb, outp);
}

// Round 12
// 208.909 us; speedup vs baseline: 2.2255x; 2.2255x over previous
//
#include <hip/hip_runtime.h>
#include <hip/hip_bf16.h>

#define DEVINL __device__ __forceinline__

typedef __attribute__((ext_vector_type(8)))  short short8;
typedef __attribute__((ext_vector_type(4)))  float float4v;

DEVINL float bf2f(unsigned short u) { return __uint_as_float(((unsigned)u) << 16); }
DEVINL unsigned short f2bf(float f) {            // round-to-nearest-even
  unsigned u = __float_as_uint(f);
  unsigned r = u + 0x7FFFu + ((u >> 16) & 1u);
  return (unsigned short)(r >> 16);
}
DEVINL unsigned short bfmax(unsigned short a, unsigned short b) {
  return (bf2f(a) > bf2f(b)) ? a : b;    // exact: bf16 round is monotone
}

// region: 0=center,1=TL,2=top,3=TR,4=right,5=BR,6=bottom,7=BL,8=left
DEVINL int region_of(int h, int w, int n) {
  if (h == 0)     return (w == 0) ? 1 : ((w == n-1) ? 3 : 2);
  if (h == n-1)   return (w == 0) ? 7 : ((w == n-1) ? 5 : 6);
  return (w == 0) ? 8 : ((w == n-1) ? 4 : 0);
}

__global__ void sentinel_k(float* out, float v) {
  int t = blockIdx.x*64 + threadIdx.x;
  if (t < 320) out[t] = v;
}

union ABu { float4 f4; short8 v; };

// ---- conv1 (C=1->64, vector ALU) + weight transposes, one kernel ----
// blocks 0..2047: conv1 units (b,h); blocks 2048..2173: wtrans items.
__global__ __launch_bounds__(256, 4) void conv1w_k(
    const float* __restrict__ x, const float* __restrict__ Wc1,
    const float* __restrict__ Dc1, unsigned short* __restrict__ U1,
    const float* __restrict__ W2, const float* __restrict__ W3,
    const float* __restrict__ W4, unsigned short* __restrict__ T2,
    unsigned short* __restrict__ T3, unsigned short* __restrict__ T4)
{
  __shared__ float a[3][66];
  int bb = blockIdx.x, t = threadIdx.x;
  if (bb >= 2048) {
    // B-frag layout: lane holds B[k=(lane>>4)*8+j][n=lane&15], j=0..7
    int i = (bb - 2048)*256 + t;
    if (i < 32256) {
      const float* W; unsigned short* T; int NT, F, li;
      if (i < 4608)       { W = W2; T = T2; NT = 4; F = 64;  li = i; }
      else if (i < 13824) { W = W3; T = T3; NT = 8; F = 128; li = i - 4608; }
      else                { W = W4; T = T4; NT = 8; F = 128; li = i - 13824; }
      int l = li & 63, nt = (li >> 6) % NT, kstep = li / (64*NT);
      int f = nt*16 + (l & 15);
      int kbase = kstep*32 + (l >> 4)*8;
      unsigned short v[8];
      #pragma unroll
      for (int j = 0; j < 8; j++) v[j] = f2bf(W[(kbase + j)*F + f]);
      ushort4* q = (ushort4*)&T[(size_t)li * 8];
      q[0] = make_ushort4(v[0], v[1], v[2], v[3]);
      q[1] = make_ushort4(v[4], v[5], v[6], v[7]);
    }
    return;
  }
  int b = bb >> 6, h = bb & 63;
  for (int idx = t; idx < 3*66; idx += 256) {
    int dy = idx / 66, wcol = idx % 66;
    int hh = h + dy - 1, w = wcol - 1;
    float v = 0.f;
    if (hh >= 0 && hh < 64 && w >= 0 && w < 64) v = x[(b*64 + hh)*64 + w];
    a[dy][wcol] = v;
  }
  __syncthreads();
  int f = t & 63, wq = t >> 6;
  float wk[9];
  #pragma unroll
  for (int k = 0; k < 9; k++) wk[k] = Wc1[k*64 + f];
  for (int wi = 0; wi < 16; wi++) {
    int w = wq*16 + wi;
    float acc = 0.f;
    #pragma unroll
    for (int dy = 0; dy < 3; dy++)
      #pragma unroll
      for (int dx = 0; dx < 3; dx++)
        acc += a[dy][w+dx] * wk[dy*3+dx];
    int r = region_of(h, w, 64);
    U1[(((size_t)b*64 + h)*64 + w)*64 + f] = f2bf(fminf(acc - Dc1[r*64 + f], 0.f));
  }
}

// ---- conv2 + fused pool: C=64,F=64,N=64. Block = (b, hp, w-half). ----
// 2048 blocks, LDS 19.6 KB -> 6 blocks/CU (launch_bounds cap), 24 waves/CU.
// Wave = (hi, mg): 1 row, 1 m-tile, all 4 n-tiles. Pool h-pairs via LDS.
__global__ __launch_bounds__(256, 6) void conv2p_k(
    const unsigned short* __restrict__ U1, const unsigned short* __restrict__ Wt2,
    const float* __restrict__ Dc2, unsigned short* __restrict__ P2)
{
  __shared__ __align__(16) unsigned short lds[4*34*72];   // 19584 B
  int bb = blockIdx.x, t = threadIdx.x;
  int wh = bb & 1, hp = (bb >> 1) & 31, b = bb >> 6;
  int h0 = hp*2, w0 = wh*32;
  for (int i = t; i < 4*34*8; i += 256) {
    int c8 = i & 7, wc = (i >> 3) % 34, r = i / (8*34);
    int hh = h0 - 1 + r, w = w0 - 1 + wc;
    float4 v = make_float4(0.f,0.f,0.f,0.f);
    if (hh >= 0 && hh < 64 && w >= 0 && w < 64)
      v = *(const float4*)&U1[(((size_t)b*64 + hh)*64 + w)*64 + c8*8];
    *(float4*)&lds[(r*34 + wc)*72 + c8*8] = v;
  }
  __syncthreads();
  int lane = t & 63, wave = t >> 6, quad = (lane >> 4), lm = lane & 15;
  int hi = wave >> 1, mg = wave & 1;
  float4v acc[4];
  #pragma unroll
  for (int n = 0; n < 4; n++) acc[n] = (float4v){0.f,0.f,0.f,0.f};
  #pragma unroll
  for (int dy = 0; dy < 3; dy++)
  #pragma unroll
  for (int dx = 0; dx < 3; dx++)
  #pragma unroll
  for (int c0 = 0; c0 < 64; c0 += 32) {
    int kstep = (dy*3 + dx)*2 + (c0 >> 5);
    ABu bfr[4];
    #pragma unroll
    for (int n = 0; n < 4; n++)
      bfr[n].f4 = *(const float4*)&Wt2[(size_t)((kstep*4 + n)*64 + lane)*8];
    ABu afr;
    afr.f4 = *(const float4*)&lds[((hi+dy)*34 + (mg*16 + lm + dx))*72 + c0 + quad*8];
    #pragma unroll
    for (int n = 0; n < 4; n++)
      acc[n] = __builtin_amdgcn_mfma_f32_16x16x32_bf16(afr.v, bfr[n].v, acc[n], 0, 0, 0);
  }
  __syncthreads();                       // all LDS reads done; reuse as pw
  unsigned short* pw = lds;              // [2][16][64]
  int h = h0 + hi;
  #pragma unroll
  for (int n = 0; n < 4; n++) {
    int f = n*16 + lm;
    #pragma unroll
    for (int rp = 0; rp < 2; rp++) {
      float v0 = fminf(acc[n][2*rp]   - Dc2[region_of(h, w0 + mg*16 + quad*4 + 2*rp,     64)*64 + f], 0.f);
      float v1 = fminf(acc[n][2*rp+1] - Dc2[region_of(h, w0 + mg*16 + quad*4 + 2*rp + 1, 64)*64 + f], 0.f);
      pw[(hi*16 + mg*8 + quad*2 + rp)*64 + f] = f2bf(fmaxf(v0, v1));
    }
  }
  __syncthreads();
  {
    int wp = t >> 4, f0 = (t & 15)*4;
    ushort4 a0 = *(ushort4*)&pw[wp*64 + f0];
    ushort4 a1 = *(ushort4*)&pw[(16 + wp)*64 + f0];
    ushort4 o;
    o.x = bfmax(a0.x, a1.x); o.y = bfmax(a0.y, a1.y);
    o.z = bfmax(a0.z, a1.z); o.w = bfmax(a0.w, a1.w);
    *(ushort4*)&P2[(((size_t)b*32 + hp)*32 + (wh*16 + wp))*64 + f0] = o;
  }
}

// ---- conv3: C=64,F=128,N=32. Block = (b, h, w-half). 2048 blocks. ----
// LDS 7.8 KB; wave = nq: 1 row, 1 m-tile, 2 n-tiles. 32 waves/CU target.
__global__ __launch_bounds__(256, 8) void conv3_k(
    const unsigned short* __restrict__ P2, const unsigned short* __restrict__ Wt3,
    const float* __restrict__ Dc3, unsigned short* __restrict__ U3)
{
  __shared__ __align__(16) unsigned short lds[3*18*72];   // 7776 B
  int bb = blockIdx.x, t = threadIdx.x;
  int wh = bb & 1, h = (bb >> 1) & 31, b = bb >> 6;
  int w0 = wh*16;
  for (int i = t; i < 3*18*8; i += 256) {
    int c8 = i & 7, wc = (i >> 3) % 18, r = i / (8*18);
    int hh = h - 1 + r, w = w0 - 1 + wc;
    float4 v = make_float4(0.f,0.f,0.f,0.f);
    if (hh >= 0 && hh < 32 && w >= 0 && w < 32)
      v = *(const float4*)&P2[(((size_t)b*32 + hh)*32 + w)*64 + c8*8];
    *(float4*)&lds[(r*18 + wc)*72 + c8*8] = v;
  }
  __syncthreads();
  int lane = t & 63, nq = t >> 6, quad = (lane >> 4), lm = lane & 15;
  float4v acc[2];
  acc[0] = (float4v){0.f,0.f,0.f,0.f};
  acc[1] = (float4v){0.f,0.f,0.f,0.f};
  #pragma unroll
  for (int dy = 0; dy < 3; dy++)
  #pragma unroll
  for (int dx = 0; dx < 3; dx++)
  #pragma unroll
  for (int c0 = 0; c0 < 64; c0 += 32) {
    int kstep = (dy*3 + dx)*2 + (c0 >> 5);
    ABu bfr[2];
    #pragma unroll
    for (int n = 0; n < 2; n++)
      bfr[n].f4 = *(const float4*)&Wt3[(size_t)((kstep*8 + nq*2 + n)*64 + lane)*8];
    ABu afr;
    afr.f4 = *(const float4*)&lds[(dy*18 + (lm + dx))*72 + c0 + quad*8];
    #pragma unroll
    for (int n = 0; n < 2; n++)
      acc[n] = __builtin_amdgcn_mfma_f32_16x16x32_bf16(afr.v, bfr[n].v, acc[n], 0, 0, 0);
  }
  #pragma unroll
  for (int n = 0; n < 2; n++) {
    int f = (nq*2 + n)*16 + lm;
    #pragma unroll
    for (int r = 0; r < 4; r++) {
      int w = w0 + quad*4 + r;
      float v = fminf(acc[n][r] - Dc3[region_of(h, w, 32)*128 + f], 0.f);
      U3[(((size_t)b*32 + h)*32 + w)*128 + f] = f2bf(v);
    }
  }
}

// ---- conv4 + fused pool: C=128,F=128,N=32. Block = (b,hp,m-half,f-half). ----
// 2048 blocks, LDS 19.6 KB. Wave = (hi, nq): 1 row, 16w, 2 n-tiles.
__global__ __launch_bounds__(256, 6) void conv4p_k(
    const unsigned short* __restrict__ U3, const unsigned short* __restrict__ Wt4,
    const float* __restrict__ Dc4, unsigned short* __restrict__ P4)
{
  __shared__ __align__(16) unsigned short lds[4*18*136];  // 19584 B
  int bb = blockIdx.x, t = threadIdx.x;
  int fh = bb & 1, mh = (bb >> 1) & 1, hp = (bb >> 2) & 15, b = bb >> 6;
  int h0 = hp*2, w0 = mh*16;
  for (int i = t; i < 4*18*16; i += 256) {
    int c8 = i & 15, wc = (i >> 4) % 18, r = i / (16*18);
    int hh = h0 - 1 + r, w = w0 - 1 + wc;
    float4 v = make_float4(0.f,0.f,0.f,0.f);
    if (hh >= 0 && hh < 32 && w >= 0 && w < 32)
      v = *(const float4*)&U3[(((size_t)b*32 + hh)*32 + w)*128 + c8*8];
    *(float4*)&lds[(r*18 + wc)*136 + c8*8] = v;
  }
  __syncthreads();
  int lane = t & 63, wave = t >> 6, quad = (lane >> 4), lm = lane & 15;
  int hi = wave >> 1, nq = wave & 1;
  float4v acc[2];
  acc[0] = (float4v){0.f,0.f,0.f,0.f};
  acc[1] = (float4v){0.f,0.f,0.f,0.f};
  #pragma unroll
  for (int dy = 0; dy < 3; dy++)
  #pragma unroll
  for (int dx = 0; dx < 3; dx++)
  #pragma unroll
  for (int c0 = 0; c0 < 128; c0 += 32) {
    int kstep = (dy*3 + dx)*4 + (c0 >> 5);
    ABu bfr[2];
    #pragma unroll
    for (int n = 0; n < 2; n++)
      bfr[n].f4 = *(const float4*)&Wt4[(size_t)((kstep*8 + fh*4 + nq*2 + n)*64 + lane)*8];
    ABu afr;
    afr.f4 = *(const float4*)&lds[((hi+dy)*18 + (lm + dx))*136 + c0 + quad*8];
    #pragma unroll
    for (int n = 0; n < 2; n++)
      acc[n] = __builtin_amdgcn_mfma_f32_16x16x32_bf16(afr.v, bfr[n].v, acc[n], 0, 0, 0);
  }
  __syncthreads();                       // reuse LDS as pw
  unsigned short* pw = lds;              // [2][8][64]
  int h = h0 + hi;
  #pragma unroll
  for (int n = 0; n < 2; n++) {
    int fl = (nq*2 + n)*16 + lm;         // 0..63 within f-half
    int f = fh*64 + fl;
    #pragma unroll
    for (int rp = 0; rp < 2; rp++) {
      float v0 = fminf(acc[n][2*rp]   - Dc4[region_of(h, w0 + quad*4 + 2*rp,     32)*128 + f], 0.f);
      float v1 = fminf(acc[n][2*rp+1] - Dc4[region_of(h, w0 + quad*4 + 2*rp + 1, 32)*128 + f], 0.f);
      pw[(hi*8 + quad*2 + rp)*64 + fl] = f2bf(fmaxf(v0, v1));
    }
  }
  __syncthreads();
  {
    int wp = t >> 5, fl0 = (t & 31)*2;
    ushort2 a0 = *(ushort2*)&pw[wp*64 + fl0];
    ushort2 a1 = *(ushort2*)&pw[(8 + wp)*64 + fl0];
    ushort2 o;
    o.x = bfmax(a0.x, a1.x); o.y = bfmax(a0.y, a1.y);
    *(ushort2*)&P4[(((size_t)b*16 + hp)*16 + (mh*8 + wp))*128 + fh*64 + fl0] = o;
  }
}

// ---- dense split-K x f-quarter: 1024 blocks ----
__global__ __launch_bounds__(256, 8) void dense_k(const unsigned short* __restrict__ act,
    const float* __restrict__ W, float* __restrict__ part)
{
  __shared__ float a[128][36];           // 18432 B
  int bb = blockIdx.x, t = threadIdx.x;
  int fq = bb & 3, kblk = bb >> 2, k0 = kblk*128;
  for (int idx = t; idx < 32*128; idx += 256) {
    int bbb = idx >> 7, kc = idx & 127;
    a[kc][bbb] = bf2f(act[(size_t)bbb*32768 + k0 + kc]);
  }
  __syncthreads();
  int f0 = fq*64 + (t & 15)*4, b0 = (t >> 4)*2;
  float acc[2][4] = {};
  for (int kc = 0; kc < 128; kc++) {
    float4 wv = *(const float4*)&W[(size_t)(k0 + kc)*256 + f0];
    #pragma unroll
    for (int bi = 0; bi < 2; bi++) {
      float av = a[kc][b0 + bi];
      acc[bi][0] += av * wv.x;
      acc[bi][1] += av * wv.y;
      acc[bi][2] += av * wv.z;
      acc[bi][3] += av * wv.w;
    }
  }
  #pragma unroll
  for (int bi = 0; bi < 2; bi++) {
    float4 v = make_float4(acc[bi][0], acc[bi][1], acc[bi][2], acc[bi][3]);
    *(float4*)&part[(size_t)kblk*8192 + (b0+bi)*256 + f0] = v;
  }
}

// ---- tail: reduce partials -> ud, then out = Dout - ud @ Wout ----
__global__ __launch_bounds__(256) void tail_k(const float* __restrict__ part,
    const float* __restrict__ Dd, const float* __restrict__ Wo,
    const float* __restrict__ Do, float* __restrict__ out)
{
  int b = blockIdx.x, t = threadIdx.x;
  __shared__ float ud[256];
  float s = 0.f;
  #pragma unroll 8
  for (int blk = 0; blk < 256; blk++) s += part[(size_t)blk*8192 + b*256 + t];
  ud[t] = fminf(s - Dd[t], 0.f);
  __syncthreads();
  if (t < 10) {
    float acc = 0.f;
    for (int f = 0; f < 256; f++) acc += ud[f] * Wo[f*10 + t];
    out[b*10 + t] = Do[t] - acc;
  }
}

extern "C" void kernel_launch(void* const* d_in, const int* in_sizes, int n_in,
                              void* d_out, int out_size, void* d_ws, size_t ws_size,
                              hipStream_t stream)
{
  float* outp = (float*)d_out;

  if (n_in != 13) { sentinel_k<<<5, 64, 0, stream>>>(outp, 200.f); return; }
  const int exp_sz[13] = {131072, 576, 576, 36864, 576, 73728, 1152,
                          147456, 1152, 8388608, 256, 2560, 10};
  for (int i = 0; i < 13; i++)
    if (in_sizes[i] != exp_sz[i]) {
      sentinel_k<<<5, 64, 0, stream>>>(outp, 1000.f + 100.f*i); return;
    }
  if (ws_size < (37u << 20)) { sentinel_k<<<5, 64, 0, stream>>>(outp, 500.f); return; }

  char* wsb = (char*)d_ws;
  const float* x    = (const float*)d_in[0];
  const float* Wc1  = (const float*)d_in[1];
  const float* Dc1  = (const float*)d_in[2];
  const float* Wc2  = (const float*)d_in[3];
  const float* Dc2  = (const float*)d_in[4];
  const float* Wc3  = (const float*)d_in[5];
  const float* Dc3  = (const float*)d_in[6];
  const float* Wc4  = (const float*)d_in[7];
  const float* Dc4  = (const float*)d_in[8];
  const float* Wd1  = (const float*)d_in[9];
  const float* Dd1  = (const float*)d_in[10];
  const float* Wout = (const float*)d_in[11];
  const float* Dout = (const float*)d_in[12];

  unsigned short* Wt2 = (unsigned short*)(wsb + (1u << 20));
  unsigned short* Wt3 = (unsigned short*)(wsb + (1u << 20) + 262144);
  unsigned short* Wt4 = (unsigned short*)(wsb + (1u << 20) + 524288);
  unsigned short* U1 = (unsigned short*)(wsb + (2u  << 20)); // 16.8 MB
  unsigned short* P2 = (unsigned short*)(wsb + (19u << 20)); // 4.2 MB
  unsigned short* U3 = (unsigned short*)(wsb + (2u  << 20)); // 8.4 MB (U1 dead)
  unsigned short* P4 = (unsigned short*)(wsb + (19u << 20)); // 2.1 MB (P2 dead)
  float* part        = (float*)(wsb + (2u  << 20));          // 8.4 MB (U3 dead)

  conv1w_k<<<2174, 256, 0, stream>>>(x, Wc1, Dc1, U1, Wc2, Wc3, Wc4, Wt2, Wt3, Wt4);
  conv2p_k<<<2048, 256, 0, stream>>>(U1, Wt2, Dc2, P2);
  conv3_k <<<2048, 256, 0, stream>>>(P2, Wt3, Dc3, U3);
  conv4p_k<<<2048, 256, 0, stream>>>(U3, Wt4, Dc4, P4);
  dense_k <<<1024, 256, 0, stream>>>(P4, Wd1, part);
  tail_k  <<<32,   256, 0, stream>>>(part, Dd1, Wout, Dout, outp);
}

// Round 13
// 196.089 us; speedup vs baseline: 2.3710x; 1.0654x over previous
//
#include <hip/hip_runtime.h>
#include <hip/hip_bf16.h>

#define DEVINL __device__ __forceinline__

typedef __attribute__((ext_vector_type(8)))  short short8;
typedef __attribute__((ext_vector_type(4)))  float float4v;

DEVINL float bf2f(unsigned short u) { return __uint_as_float(((unsigned)u) << 16); }
DEVINL unsigned short f2bf(float f) {            // round-to-nearest-even
  unsigned u = __float_as_uint(f);
  unsigned r = u + 0x7FFFu + ((u >> 16) & 1u);
  return (unsigned short)(r >> 16);
}

// region: 0=center,1=TL,2=top,3=TR,4=right,5=BR,6=bottom,7=BL,8=left
DEVINL int region_of(int h, int w, int n) {
  if (h == 0)     return (w == 0) ? 1 : ((w == n-1) ? 3 : 2);
  if (h == n-1)   return (w == 0) ? 7 : ((w == n-1) ? 5 : 6);
  return (w == 0) ? 8 : ((w == n-1) ? 4 : 0);
}

__global__ void sentinel_k(float* out, float v) {
  int t = blockIdx.x*64 + threadIdx.x;
  if (t < 320) out[t] = v;
}

union ABu { float4 f4; short8 v; };

// ---- conv1 (C=1->64, vector ALU) + weight transposes, one kernel ----
__global__ __launch_bounds__(256, 4) void conv1w_k(
    const float* __restrict__ x, const float* __restrict__ Wc1,
    const float* __restrict__ Dc1, unsigned short* __restrict__ U1,
    const float* __restrict__ W2, const float* __restrict__ W3,
    const float* __restrict__ W4, unsigned short* __restrict__ T2,
    unsigned short* __restrict__ T3, unsigned short* __restrict__ T4)
{
  __shared__ float a[3][66];
  int bb = blockIdx.x, t = threadIdx.x;
  if (bb >= 2048) {
    // B-frag layout: lane holds B[k=(lane>>4)*8+j][n=lane&15], j=0..7
    int i = (bb - 2048)*256 + t;
    if (i < 32256) {
      const float* W; unsigned short* T; int NT, F, li;
      if (i < 4608)       { W = W2; T = T2; NT = 4; F = 64;  li = i; }
      else if (i < 13824) { W = W3; T = T3; NT = 8; F = 128; li = i - 4608; }
      else                { W = W4; T = T4; NT = 8; F = 128; li = i - 13824; }
      int l = li & 63, nt = (li >> 6) % NT, kstep = li / (64*NT);
      int f = nt*16 + (l & 15);
      int kbase = kstep*32 + (l >> 4)*8;
      unsigned short v[8];
      #pragma unroll
      for (int j = 0; j < 8; j++) v[j] = f2bf(W[(kbase + j)*F + f]);
      ushort4* q = (ushort4*)&T[(size_t)li * 8];
      q[0] = make_ushort4(v[0], v[1], v[2], v[3]);
      q[1] = make_ushort4(v[4], v[5], v[6], v[7]);
    }
    return;
  }
  int b = bb >> 6, h = bb & 63;
  for (int idx = t; idx < 3*66; idx += 256) {
    int dy = idx / 66, wcol = idx % 66;
    int hh = h + dy - 1, w = wcol - 1;
    float v = 0.f;
    if (hh >= 0 && hh < 64 && w >= 0 && w < 64) v = x[(b*64 + hh)*64 + w];
    a[dy][wcol] = v;
  }
  __syncthreads();
  int f = t & 63, wq = t >> 6;
  float wk[9];
  #pragma unroll
  for (int k = 0; k < 9; k++) wk[k] = Wc1[k*64 + f];
  for (int wi = 0; wi < 16; wi++) {
    int w = wq*16 + wi;
    float acc = 0.f;
    #pragma unroll
    for (int dy = 0; dy < 3; dy++)
      #pragma unroll
      for (int dx = 0; dx < 3; dx++)
        acc += a[dy][w+dx] * wk[dy*3+dx];
    int r = region_of(h, w, 64);
    U1[(((size_t)b*64 + h)*64 + w)*64 + f] = f2bf(fminf(acc - Dc1[r*64 + f], 0.f));
  }
}

// ---- conv2 + in-register pool: C=64,F=64,N=64. Block=(b,hp), 128 thr. ----
// Wave (2 of them) = 2 rows x 2 m-tiles x 4 n-tiles: 16 MFMA per (4 B-frag
// loads + 4 A ds_reads) -> B-bytes/MFMA = 0.25 KB (R12 had 1 KB: L2-bound).
// Pool: h-pair in-wave, w-pair in-lane -> pure register max.
__global__ __launch_bounds__(128) void conv2p_k(
    const unsigned short* __restrict__ U1, const unsigned short* __restrict__ Wt2,
    const float* __restrict__ Dc2, unsigned short* __restrict__ P2)
{
  __shared__ __align__(16) unsigned short lds[4*66*72];   // 38016 B
  int bb = blockIdx.x, t = threadIdx.x;
  int b = bb >> 5, hp = bb & 31, h0 = hp*2;
  for (int i = t; i < 4*66*8; i += 128) {
    int c8 = i & 7, wc = (i >> 3) % 66, r = i / (8*66);
    int hh = h0 - 1 + r, w = wc - 1;
    float4 v = make_float4(0.f,0.f,0.f,0.f);
    if (hh >= 0 && hh < 64 && w >= 0 && w < 64)
      v = *(const float4*)&U1[(((size_t)b*64 + hh)*64 + w)*64 + c8*8];
    *(float4*)&lds[(r*66 + wc)*72 + c8*8] = v;
  }
  __syncthreads();
  int lane = t & 63, mg = t >> 6, quad = lane >> 4, lm = lane & 15;
  float4v acc[2][2][4];                  // [hi][ml][n] = 64 VGPR
  #pragma unroll
  for (int hi = 0; hi < 2; hi++)
    #pragma unroll
    for (int ml = 0; ml < 2; ml++)
      #pragma unroll
      for (int n = 0; n < 4; n++) acc[hi][ml][n] = (float4v){0.f,0.f,0.f,0.f};
  #pragma unroll
  for (int dy = 0; dy < 3; dy++)
  #pragma unroll 1
  for (int dx = 0; dx < 3; dx++)
  #pragma unroll
  for (int c0 = 0; c0 < 64; c0 += 32) {
    int kstep = (dy*3 + dx)*2 + (c0 >> 5);
    ABu bfr[4];
    #pragma unroll
    for (int n = 0; n < 4; n++)
      bfr[n].f4 = *(const float4*)&Wt2[(size_t)((kstep*4 + n)*64 + lane)*8];
    ABu afr[2][2];
    #pragma unroll
    for (int hi = 0; hi < 2; hi++)
      #pragma unroll
      for (int ml = 0; ml < 2; ml++)
        afr[hi][ml].f4 = *(const float4*)&lds[((hi+dy)*66 + ((mg*2+ml)*16 + lm + dx))*72 + c0 + quad*8];
    #pragma unroll
    for (int hi = 0; hi < 2; hi++)
      #pragma unroll
      for (int ml = 0; ml < 2; ml++)
        #pragma unroll
        for (int n = 0; n < 4; n++)
          acc[hi][ml][n] = __builtin_amdgcn_mfma_f32_16x16x32_bf16(afr[hi][ml].v, bfr[n].v, acc[hi][ml][n], 0, 0, 0);
  }
  // epilogue: D layout col=lane&15 (f), row=quad*4+r (w); pool 2x2 in-register
  #pragma unroll
  for (int ml = 0; ml < 2; ml++) {
    int m = mg*2 + ml;
    #pragma unroll
    for (int n = 0; n < 4; n++) {
      int f = n*16 + lm;
      #pragma unroll
      for (int rp = 0; rp < 2; rp++) {
        float mx = -1e30f;
        #pragma unroll
        for (int hi = 0; hi < 2; hi++)
          #pragma unroll
          for (int rr = 0; rr < 2; rr++) {
            int h = h0 + hi, w = m*16 + quad*4 + 2*rp + rr;
            mx = fmaxf(mx, fminf(acc[hi][ml][n][2*rp+rr] - Dc2[region_of(h, w, 64)*64 + f], 0.f));
          }
        P2[(((size_t)b*32 + hp)*32 + (m*8 + quad*2 + rp))*64 + f] = f2bf(mx);
      }
    }
  }
}

// ---- conv3: C=64,F=128,N=32. Block=(b,h,n-half), 64 thr = 1 wave. ----
// Wave = 1 row x 2 m-tiles (full 32 w) x 4 n-tiles. 2048 blocks, 8/CU.
__global__ __launch_bounds__(64) void conv3_k(
    const unsigned short* __restrict__ P2, const unsigned short* __restrict__ Wt3,
    const float* __restrict__ Dc3, unsigned short* __restrict__ U3)
{
  __shared__ __align__(16) unsigned short lds[3*34*72];   // 14688 B
  int bb = blockIdx.x, t = threadIdx.x;
  int nh = bb & 1, h = (bb >> 1) & 31, b = bb >> 6;
  for (int i = t; i < 3*34*8; i += 64) {
    int c8 = i & 7, wc = (i >> 3) % 34, r = i / (8*34);
    int hh = h - 1 + r, w = wc - 1;
    float4 v = make_float4(0.f,0.f,0.f,0.f);
    if (hh >= 0 && hh < 32 && w >= 0 && w < 32)
      v = *(const float4*)&P2[(((size_t)b*32 + hh)*32 + w)*64 + c8*8];
    *(float4*)&lds[(r*34 + wc)*72 + c8*8] = v;
  }
  __syncthreads();
  int lane = t, quad = lane >> 4, lm = lane & 15;
  float4v acc[2][4];                     // [ml][n] = 32 VGPR
  #pragma unroll
  for (int ml = 0; ml < 2; ml++)
    #pragma unroll
    for (int n = 0; n < 4; n++) acc[ml][n] = (float4v){0.f,0.f,0.f,0.f};
  #pragma unroll
  for (int dy = 0; dy < 3; dy++)
  #pragma unroll 1
  for (int dx = 0; dx < 3; dx++)
  #pragma unroll
  for (int c0 = 0; c0 < 64; c0 += 32) {
    int kstep = (dy*3 + dx)*2 + (c0 >> 5);
    ABu bfr[4];
    #pragma unroll
    for (int n = 0; n < 4; n++)
      bfr[n].f4 = *(const float4*)&Wt3[(size_t)((kstep*8 + nh*4 + n)*64 + lane)*8];
    ABu afr[2];
    #pragma unroll
    for (int ml = 0; ml < 2; ml++)
      afr[ml].f4 = *(const float4*)&lds[(dy*34 + (ml*16 + lm + dx))*72 + c0 + quad*8];
    #pragma unroll
    for (int ml = 0; ml < 2; ml++)
      #pragma unroll
      for (int n = 0; n < 4; n++)
        acc[ml][n] = __builtin_amdgcn_mfma_f32_16x16x32_bf16(afr[ml].v, bfr[n].v, acc[ml][n], 0, 0, 0);
  }
  #pragma unroll
  for (int ml = 0; ml < 2; ml++)
    #pragma unroll
    for (int n = 0; n < 4; n++) {
      int f = (nh*4 + n)*16 + lm;
      #pragma unroll
      for (int r = 0; r < 4; r++) {
        int w = ml*16 + quad*4 + r;
        float v = fminf(acc[ml][n][r] - Dc3[region_of(h, w, 32)*128 + f], 0.f);
        U3[(((size_t)b*32 + h)*32 + w)*128 + f] = f2bf(v);
      }
    }
}

// ---- conv4 + in-register pool: C=128,F=128,N=32. Block=(b,hp), 256 thr. ----
// Wave = (nq): 2 rows x 2 m-tiles (full 32 w) x 2 n-tiles: 8 MFMA per
// (2 B-frags + 4 A ds_reads) -> 0.25 KB B/MFMA. Pool in-register.
__global__ __launch_bounds__(256) void conv4p_k(
    const unsigned short* __restrict__ U3, const unsigned short* __restrict__ Wt4,
    const float* __restrict__ Dc4, unsigned short* __restrict__ P4)
{
  __shared__ __align__(16) unsigned short lds[4*34*136];  // 36992 B
  int bb = blockIdx.x, t = threadIdx.x;
  int b = bb >> 4, hp = bb & 15, h0 = hp*2;
  for (int i = t; i < 4*34*16; i += 256) {
    int c8 = i & 15, wc = (i >> 4) % 34, r = i / (16*34);
    int hh = h0 - 1 + r, w = wc - 1;
    float4 v = make_float4(0.f,0.f,0.f,0.f);
    if (hh >= 0 && hh < 32 && w >= 0 && w < 32)
      v = *(const float4*)&U3[(((size_t)b*32 + hh)*32 + w)*128 + c8*8];
    *(float4*)&lds[(r*34 + wc)*136 + c8*8] = v;
  }
  __syncthreads();
  int lane = t & 63, nq = t >> 6, quad = lane >> 4, lm = lane & 15;
  float4v acc[2][2][2];                  // [hi][ml][n] = 32 VGPR
  #pragma unroll
  for (int hi = 0; hi < 2; hi++)
    #pragma unroll
    for (int ml = 0; ml < 2; ml++)
      #pragma unroll
      for (int n = 0; n < 2; n++) acc[hi][ml][n] = (float4v){0.f,0.f,0.f,0.f};
  #pragma unroll
  for (int dy = 0; dy < 3; dy++)
  #pragma unroll 1
  for (int dx = 0; dx < 3; dx++)
  #pragma unroll 2
  for (int c0 = 0; c0 < 128; c0 += 32) {
    int kstep = (dy*3 + dx)*4 + (c0 >> 5);
    ABu bfr[2];
    #pragma unroll
    for (int n = 0; n < 2; n++)
      bfr[n].f4 = *(const float4*)&Wt4[(size_t)((kstep*8 + nq*2 + n)*64 + lane)*8];
    ABu afr[2][2];
    #pragma unroll
    for (int hi = 0; hi < 2; hi++)
      #pragma unroll
      for (int ml = 0; ml < 2; ml++)
        afr[hi][ml].f4 = *(const float4*)&lds[((hi+dy)*34 + (ml*16 + lm + dx))*136 + c0 + quad*8];
    #pragma unroll
    for (int hi = 0; hi < 2; hi++)
      #pragma unroll
      for (int ml = 0; ml < 2; ml++)
        #pragma unroll
        for (int n = 0; n < 2; n++)
          acc[hi][ml][n] = __builtin_amdgcn_mfma_f32_16x16x32_bf16(afr[hi][ml].v, bfr[n].v, acc[hi][ml][n], 0, 0, 0);
  }
  #pragma unroll
  for (int ml = 0; ml < 2; ml++)
    #pragma unroll
    for (int n = 0; n < 2; n++) {
      int f = (nq*2 + n)*16 + lm;
      #pragma unroll
      for (int rp = 0; rp < 2; rp++) {
        float mx = -1e30f;
        #pragma unroll
        for (int hi = 0; hi < 2; hi++)
          #pragma unroll
          for (int rr = 0; rr < 2; rr++) {
            int h = h0 + hi, w = ml*16 + quad*4 + 2*rp + rr;
            mx = fmaxf(mx, fminf(acc[hi][ml][n][2*rp+rr] - Dc4[region_of(h, w, 32)*128 + f], 0.f));
          }
        P4[(((size_t)b*16 + hp)*16 + (ml*8 + quad*2 + rp))*128 + f] = f2bf(mx);
      }
    }
}

// ---- dense split-K x f-quarter: 1024 blocks ----
__global__ __launch_bounds__(256, 8) void dense_k(const unsigned short* __restrict__ act,
    const float* __restrict__ W, float* __restrict__ part)
{
  __shared__ float a[128][36];           // 18432 B
  int bb = blockIdx.x, t = threadIdx.x;
  int fq = bb & 3, kblk = bb >> 2, k0 = kblk*128;
  for (int idx = t; idx < 32*128; idx += 256) {
    int bbb = idx >> 7, kc = idx & 127;
    a[kc][bbb] = bf2f(act[(size_t)bbb*32768 + k0 + kc]);
  }
  __syncthreads();
  int f0 = fq*64 + (t & 15)*4, b0 = (t >> 4)*2;
  float acc[2][4] = {};
  for (int kc = 0; kc < 128; kc++) {
    float4 wv = *(const float4*)&W[(size_t)(k0 + kc)*256 + f0];
    #pragma unroll
    for (int bi = 0; bi < 2; bi++) {
      float av = a[kc][b0 + bi];
      acc[bi][0] += av * wv.x;
      acc[bi][1] += av * wv.y;
      acc[bi][2] += av * wv.z;
      acc[bi][3] += av * wv.w;
    }
  }
  #pragma unroll
  for (int bi = 0; bi < 2; bi++) {
    float4 v = make_float4(acc[bi][0], acc[bi][1], acc[bi][2], acc[bi][3]);
    *(float4*)&part[(size_t)kblk*8192 + (b0+bi)*256 + f0] = v;
  }
}

// ---- tail: reduce partials -> ud, then out = Dout - ud @ Wout ----
__global__ __launch_bounds__(256) void tail_k(const float* __restrict__ part,
    const float* __restrict__ Dd, const float* __restrict__ Wo,
    const float* __restrict__ Do, float* __restrict__ out)
{
  int b = blockIdx.x, t = threadIdx.x;
  __shared__ float ud[256];
  float s = 0.f;
  #pragma unroll 8
  for (int blk = 0; blk < 256; blk++) s += part[(size_t)blk*8192 + b*256 + t];
  ud[t] = fminf(s - Dd[t], 0.f);
  __syncthreads();
  if (t < 10) {
    float acc = 0.f;
    for (int f = 0; f < 256; f++) acc += ud[f] * Wo[f*10 + t];
    out[b*10 + t] = Do[t] - acc;
  }
}

extern "C" void kernel_launch(void* const* d_in, const int* in_sizes, int n_in,
                              void* d_out, int out_size, void* d_ws, size_t ws_size,
                              hipStream_t stream)
{
  float* outp = (float*)d_out;

  if (n_in != 13) { sentinel_k<<<5, 64, 0, stream>>>(outp, 200.f); return; }
  const int exp_sz[13] = {131072, 576, 576, 36864, 576, 73728, 1152,
                          147456, 1152, 8388608, 256, 2560, 10};
  for (int i = 0; i < 13; i++)
    if (in_sizes[i] != exp_sz[i]) {
      sentinel_k<<<5, 64, 0, stream>>>(outp, 1000.f + 100.f*i); return;
    }
  if (ws_size < (37u << 20)) { sentinel_k<<<5, 64, 0, stream>>>(outp, 500.f); return; }

  char* wsb = (char*)d_ws;
  const float* x    = (const float*)d_in[0];
  const float* Wc1  = (const float*)d_in[1];
  const float* Dc1  = (const float*)d_in[2];
  const float* Wc2  = (const float*)d_in[3];
  const float* Dc2  = (const float*)d_in[4];
  const float* Wc3  = (const float*)d_in[5];
  const float* Dc3  = (const float*)d_in[6];
  const float* Wc4  = (const float*)d_in[7];
  const float* Dc4  = (const float*)d_in[8];
  const float* Wd1  = (const float*)d_in[9];
  const float* Dd1  = (const float*)d_in[10];
  const float* Wout = (const float*)d_in[11];
  const float* Dout = (const float*)d_in[12];

  unsigned short* Wt2 = (unsigned short*)(wsb + (1u << 20));
  unsigned short* Wt3 = (unsigned short*)(wsb + (1u << 20) + 262144);
  unsigned short* Wt4 = (unsigned short*)(wsb + (1u << 20) + 524288);
  unsigned short* U1 = (unsigned short*)(wsb + (2u  << 20)); // 16.8 MB
  unsigned short* P2 = (unsigned short*)(wsb + (19u << 20)); // 4.2 MB
  unsigned short* U3 = (unsigned short*)(wsb + (2u  << 20)); // 8.4 MB (U1 dead)
  unsigned short* P4 = (unsigned short*)(wsb + (19u << 20)); // 2.1 MB (P2 dead)
  float* part        = (float*)(wsb + (2u  << 20));          // 8.4 MB (U3 dead)

  conv1w_k<<<2174, 256, 0, stream>>>(x, Wc1, Dc1, U1, Wc2, Wc3, Wc4, Wt2, Wt3, Wt4);
  conv2p_k<<<1024, 128, 0, stream>>>(U1, Wt2, Dc2, P2);
  conv3_k <<<2048, 64,  0, stream>>>(P2, Wt3, Dc3, U3);
  conv4p_k<<<512,  256, 0, stream>>>(U3, Wt4, Dc4, P4);
  dense_k <<<1024, 256, 0, stream>>>(P4, Wd1, part);
  tail_k  <<<32,   256, 0, stream>>>(part, Dd1, Wout, Dout, outp);
}